// Round 14
// baseline (136.172 us; speedup 1.0000x reference)
//
#include <hip/hip_runtime.h>
#include <hip/hip_bf16.h>

typedef unsigned short u16;
typedef unsigned int   u32;
typedef __attribute__((ext_vector_type(8))) short bf16x8;
typedef __attribute__((ext_vector_type(4))) float f32x4;
typedef __attribute__((ext_vector_type(16))) float f32x16;

#define SEQ     2048
#define DM      1024
#define NH      16
#define DKH     64
#define PER_SRC 4194304              // 4096*1024

// workspace layout (bytes)
#define OFF_AOH  8388608u
#define OFF_WQT  25165824u
#define OFF_WOT  27262976u
#define OFF_QH   29360128u
#define OFF_KH   37748736u
#define OFF_PML  46137344u           // old vh region (never written now)
#define OFF_PO   54525952u           // 2 parts * 8388608 B bf16 partial O
#define OFF_VT   71303168u           // vt AFTER pOb (gemm_qkv writes it; xb live)
#define NEED_WS  79691776u
#define PART_O_U 4194304             // u16 elements per pO part
#define PART_ML_F 131072             // floats per pml part (65536 rows * 2)

__device__ __forceinline__ u16 f2bf(float f) {
    union { float f; u32 u; } c; c.f = f;
    return (u16)((c.u + 0x7fffu + ((c.u >> 16) & 1u)) >> 16);
}

__device__ __forceinline__ float bf2f(u16 h) {
    union { u32 u; float f; } c; c.u = (u32)h << 16;
    return c.f;
}

__device__ __forceinline__ u32 cvt_pk_bf16(float lo, float hi) {
    u32 r;
    asm("v_cvt_pk_bf16_f32 %0, %1, %2" : "=v"(r) : "v"(lo), "v"(hi));
    return r;
}

__device__ __forceinline__ void gload_lds16(const void* g, void* l) {
    __builtin_amdgcn_global_load_lds((__attribute__((address_space(1))) void*)g,
                                     (__attribute__((address_space(3))) void*)l,
                                     16, 0, 0);
}

// ---------------- prep: cast q/k/v fp32->bf16  +  transpose-cast W ----------
__global__ void prep(const float* __restrict__ q, const float* __restrict__ k,
                     const float* __restrict__ v, const float* __restrict__ Wq,
                     const float* __restrict__ Wo, u16* __restrict__ xb,
                     u16* __restrict__ Wqt, u16* __restrict__ Wot) {
    int bid = blockIdx.x;
    int tid = threadIdx.x;
    if (bid < 6144) {
        int srcid = bid >> 11;
        const float* src = (srcid == 0) ? q : (srcid == 1) ? k : v;
        u16* dst = xb + (size_t)srcid * PER_SRC;
        size_t i = ((size_t)(bid & 2047) * 256 + tid) * 8;
        float4 a = *(const float4*)(src + i);
        float4 b = *(const float4*)(src + i + 4);
        bf16x8 o;
        o[0] = (short)f2bf(a.x); o[1] = (short)f2bf(a.y);
        o[2] = (short)f2bf(a.z); o[3] = (short)f2bf(a.w);
        o[4] = (short)f2bf(b.x); o[5] = (short)f2bf(b.y);
        o[6] = (short)f2bf(b.z); o[7] = (short)f2bf(b.w);
        *(bf16x8*)(dst + i) = o;
    } else {
        int b2 = bid - 6144;
        const float* W = (b2 >= 256) ? Wo : Wq;
        u16* Wt       = (b2 >= 256) ? Wot : Wqt;
        int bx = b2 & 255;
        int k0 = (bx & 15) * 64;
        int n0 = (bx >> 4) * 64;
        __shared__ __align__(16) float t[64][68];
        int r = tid >> 2, cs = (tid & 3) * 16;
        #pragma unroll
        for (int j = 0; j < 4; ++j) {
            float4 vv = *(const float4*)(W + (size_t)(k0 + r) * DM + n0 + cs + j * 4);
            *(float4*)&t[r][cs + j * 4] = vv;
        }
        __syncthreads();
        bf16x8 o0, o1;
        #pragma unroll
        for (int j = 0; j < 8; ++j) o0[j] = (short)f2bf(t[cs + j][r]);
        #pragma unroll
        for (int j = 0; j < 8; ++j) o1[j] = (short)f2bf(t[cs + 8 + j][r]);
        u16* dst = Wt + (size_t)(n0 + r) * DM + k0 + cs;
        *(bf16x8*)(dst)     = o0;
        *(bf16x8*)(dst + 8) = o1;
    }
}

// ---------------- projection GEMM: qkv = X * Wqt^T + bq ----------------------
// 128x128 tiles, XCD-affinity swizzle. z=0 -> qh, z=1 -> kh ([B,H,S,64]);
// z=2 -> vt DIRECTLY in [BH,64,S'] chunk-permuted layout (sperm = swap bits
// 2<->3 of s&15), replacing the old vtrans kernel.
__global__ __launch_bounds__(256)
void gemm_qkv(const u16* __restrict__ Abase, const u16* __restrict__ Bt,
              const float* __restrict__ bias, u16* __restrict__ qkbase,
              u16* __restrict__ vt)
{
    __shared__ __align__(16) u16 Alds[128 * 64];
    __shared__ __align__(16) u16 Blds[128 * 64];

    const int tid  = threadIdx.x;
    const int wave = tid >> 6;
    const int lane = tid & 63;
    const int low4 = lane & 15;
    const int quad = lane >> 4;
    const int bid  = blockIdx.x;
    const int xcd  = bid & 7;
    const int j    = bid >> 3;
    const int m0 = (xcd * 4 + (j >> 3)) * 128;
    const int n0 = (j & 7) * 128;
    const int wm = (wave >> 1) * 64, wn = (wave & 1) * 64;

    const u16* A = Abase + (size_t)blockIdx.z * PER_SRC;

    f32x4 acc[4][4] = {};

    for (int kt = 0; kt < DM / 64; ++kt) {
        #pragma unroll
        for (int it = 0; it < 4; ++it) {
            int seg  = it * 256 + tid;
            int row  = seg >> 3;
            int slot = seg & 7;
            int ss   = slot ^ (row & 7);
            gload_lds16(A + (size_t)(m0 + row) * DM + kt * 64 + ss * 8,
                        &Alds[(it * 256 + wave * 64) * 8]);
            gload_lds16(Bt + (size_t)(n0 + row) * DM + kt * 64 + ss * 8,
                        &Blds[(it * 256 + wave * 64) * 8]);
        }
        __syncthreads();
        #pragma unroll
        for (int kk = 0; kk < 2; ++kk) {
            bf16x8 af[4], bfr[4];
            #pragma unroll
            for (int mi = 0; mi < 4; ++mi) {
                int row = wm + mi * 16 + low4;
                af[mi] = *(const bf16x8*)&Alds[row * 64 + (((kk * 4 + quad) ^ (row & 7)) * 8)];
            }
            #pragma unroll
            for (int ni = 0; ni < 4; ++ni) {
                int row = wn + ni * 16 + low4;
                bfr[ni] = *(const bf16x8*)&Blds[row * 64 + (((kk * 4 + quad) ^ (row & 7)) * 8)];
            }
            #pragma unroll
            for (int mi = 0; mi < 4; ++mi)
                #pragma unroll
                for (int ni = 0; ni < 4; ++ni)
                    acc[mi][ni] = __builtin_amdgcn_mfma_f32_16x16x32_bf16(
                        af[mi], bfr[ni], acc[mi][ni], 0, 0, 0);
        }
        __syncthreads();
    }

    #pragma unroll
    for (int mi = 0; mi < 4; ++mi) {
        #pragma unroll
        for (int ni = 0; ni < 4; ++ni) {
            int n = n0 + wn + ni * 16 + low4;
            float bv = bias[n];
            int h = n >> 6, dd = n & 63;
            #pragma unroll
            for (int j2 = 0; j2 < 4; ++j2) {
                int m = m0 + wm + mi * 16 + quad * 4 + j2;
                float val = acc[mi][ni][j2] + bv;
                int b = m >> 11, s = m & (SEQ - 1);
                if (blockIdx.z == 2) {
                    int sperm = (s & ~15) | ((s & 4) << 1) | ((s & 8) >> 1) | (s & 3);
                    vt[((size_t)(b * NH + h) * DKH + dd) * SEQ + sperm] = f2bf(val);
                } else {
                    u16* dst = qkbase + (size_t)blockIdx.z * PER_SRC;
                    dst[(size_t)(b * NH + h) * (SEQ * DKH) + (size_t)s * DKH + dd] = f2bf(val);
                }
            }
        }
    }
}

// ---------------- out-projection GEMM: out = AO * Wot^T + bo (fp32) ----------
// 64x128 tiles, XCD-affinity. MERGE=0: A = aoh. MERGE=1: A = two bf16 partials
// merged in-staging with per-row weights from an LDS table.
template<int MERGE>
__global__ __launch_bounds__(256)
void gemm_o(const u16* __restrict__ Abf, const u16* __restrict__ pOb,
            const float* __restrict__ pml, const u16* __restrict__ Bt,
            const float* __restrict__ bias, float* __restrict__ out)
{
    __shared__ __align__(16) u16 Alds[64 * 64];
    __shared__ __align__(16) u16 Blds[128 * 64];
    __shared__ __align__(16) float wlds[NH * 64 * 2];

    const int tid  = threadIdx.x;
    const int wave = tid >> 6;
    const int lane = tid & 63;
    const int low4 = lane & 15;
    const int quad = lane >> 4;
    const int bid  = blockIdx.x;
    const int xcd  = bid & 7;
    const int j    = bid >> 3;           // 0..63
    const int m0 = (xcd * 8 + (j >> 3)) * 64;
    const int n0 = (j & 7) * 128;
    const int wm = (wave >> 1) * 32, wn = (wave & 1) * 64;

    const int b      = m0 >> 11;
    const int s_base = m0 & (SEQ - 1);

    if (MERGE == 1) {
        #pragma unroll
        for (int idx = tid; idx < NH * 64; idx += 256) {
            int h  = idx >> 6;
            int sl = idx & 63;
            size_t row = (((size_t)(b * NH + h)) << 11) + s_base + sl;
            float2 ml1 = *(const float2*)&pml[row * 2];
            float2 ml2 = *(const float2*)&pml[PART_ML_F + row * 2];
            float m  = fmaxf(ml1.x, ml2.x);
            float w1 = __builtin_amdgcn_exp2f(ml1.x - m);
            float w2 = __builtin_amdgcn_exp2f(ml2.x - m);
            float inv = 1.0f / (ml1.y * w1 + ml2.y * w2);
            wlds[idx * 2]     = w1 * inv;
            wlds[idx * 2 + 1] = w2 * inv;
        }
        __syncthreads();
    }

    f32x4 acc[2][4] = {};

    for (int kt = 0; kt < DM / 64; ++kt) {
        #pragma unroll
        for (int it = 0; it < 2; ++it) {
            int seg  = it * 256 + tid;
            int row  = seg >> 3;             // 0..63
            int slot = seg & 7;
            int ss   = slot ^ (row & 7);
            size_t arow = (((size_t)(b * NH + kt)) << 11) + s_base + row;
            if (MERGE == 0) {
                gload_lds16(Abf + arow * DKH + ss * 8, &Alds[seg * 8]);
            } else {
                const u16* s1 = pOb + arow * DKH + ss * 8;
                const u16* s2 = s1 + PART_O_U;
                bf16x8 x = *(const bf16x8*)s1;
                bf16x8 y = *(const bf16x8*)s2;
                float a1 = wlds[(kt * 64 + row) * 2];
                float a2 = wlds[(kt * 64 + row) * 2 + 1];
                uint4 pv;
                pv.x = cvt_pk_bf16(bf2f((u16)x[0]) * a1 + bf2f((u16)y[0]) * a2,
                                   bf2f((u16)x[1]) * a1 + bf2f((u16)y[1]) * a2);
                pv.y = cvt_pk_bf16(bf2f((u16)x[2]) * a1 + bf2f((u16)y[2]) * a2,
                                   bf2f((u16)x[3]) * a1 + bf2f((u16)y[3]) * a2);
                pv.z = cvt_pk_bf16(bf2f((u16)x[4]) * a1 + bf2f((u16)y[4]) * a2,
                                   bf2f((u16)x[5]) * a1 + bf2f((u16)y[5]) * a2);
                pv.w = cvt_pk_bf16(bf2f((u16)x[6]) * a1 + bf2f((u16)y[6]) * a2,
                                   bf2f((u16)x[7]) * a1 + bf2f((u16)y[7]) * a2);
                *(uint4*)&Alds[seg * 8] = pv;
            }
        }
        #pragma unroll
        for (int it = 0; it < 4; ++it) {
            int seg  = it * 256 + tid;
            int row  = seg >> 3;             // 0..127
            int slot = seg & 7;
            int ss   = slot ^ (row & 7);
            gload_lds16(Bt + (size_t)(n0 + row) * DM + kt * 64 + ss * 8,
                        &Blds[seg * 8]);
        }
        __syncthreads();
        #pragma unroll
        for (int kk = 0; kk < 2; ++kk) {
            bf16x8 af[2], bfr[4];
            #pragma unroll
            for (int mi = 0; mi < 2; ++mi) {
                int row = wm + mi * 16 + low4;
                af[mi] = *(const bf16x8*)&Alds[row * 64 + (((kk * 4 + quad) ^ (row & 7)) * 8)];
            }
            #pragma unroll
            for (int ni = 0; ni < 4; ++ni) {
                int row = wn + ni * 16 + low4;
                bfr[ni] = *(const bf16x8*)&Blds[row * 64 + (((kk * 4 + quad) ^ (row & 7)) * 8)];
            }
            #pragma unroll
            for (int mi = 0; mi < 2; ++mi)
                #pragma unroll
                for (int ni = 0; ni < 4; ++ni)
                    acc[mi][ni] = __builtin_amdgcn_mfma_f32_16x16x32_bf16(
                        af[mi], bfr[ni], acc[mi][ni], 0, 0, 0);
        }
        __syncthreads();
    }

    #pragma unroll
    for (int mi = 0; mi < 2; ++mi) {
        #pragma unroll
        for (int ni = 0; ni < 4; ++ni) {
            int n = n0 + wn + ni * 16 + low4;
            float bv = bias[n];
            #pragma unroll
            for (int j2 = 0; j2 < 4; ++j2) {
                int m = m0 + wm + mi * 16 + quad * 4 + j2;
                out[(size_t)m * DM + n] = acc[mi][ni][j2] + bv;
            }
        }
    }
}

// ---------------- flash attention: 512 threads (8 waves share one K/V stage) -
// SPLIT=0: full pass (32 KV tiles), normalized bf16 -> aoh.
// SPLIT=1: 2-way KV split (blockIdx.y = part, 16 tiles each); UNNORMALIZED bf16
//          O~ -> pOb[part] + per-row (m,l) -> pml[part]; merged in gemm_o.
template<int SPLIT>
__global__ __launch_bounds__(512, 2)
void attn(const u16* __restrict__ qh, const u16* __restrict__ kh,
          const u16* __restrict__ vt, u16* __restrict__ aoh,
          u16* __restrict__ pOb, float* __restrict__ pml)
{
    __shared__ __align__(16) u16 lds[2][8192];   // [buf][K 4096 | V 4096]

    const int tid  = threadIdx.x;
    const int w    = tid >> 6;                   // 0..7
    const int lane = tid & 63;
    const int l31  = lane & 31;
    const int hi   = lane >> 5;

    int bid = blockIdx.x;                        // 256 blocks
    int lid = (bid & 7) * 32 + (bid >> 3);       // XCD-chunked swizzle
    const int qt = lid & 7;
    const int bh = lid >> 3;
    const int part = SPLIT ? blockIdx.y : 0;
    const int kt0  = SPLIT ? part * 16 : 0;
    const int nkt  = SPLIT ? 16 : 32;

    const int qbase = qt * 256 + w * 32;
    const int q_row = qbase + l31;

    const float SC = 0.18033688f;   // 0.125 * log2(e)

    bf16x8 qf[4];
    #pragma unroll
    for (int c = 0; c < 4; ++c)
        qf[c] = *(const bf16x8*)&qh[((size_t)bh * SEQ + q_row) * DKH + c * 16 + hi * 8];

    float m_r = -1e30f, l_r = 0.f;
    f32x16 ot[2] = {};    // O^T: col q = l31, rows d = (r&3)+8*(r>>2)+4*hi+32*dt

#define STAGE(buf, kt_)                                                                 \
    {                                                                                   \
        int row  = tid >> 3;                                                            \
        int slot = tid & 7;                                                             \
        int ss   = slot ^ (row & 7);                                                    \
        gload_lds16(kh + ((size_t)bh * SEQ + (kt_) * 64 + row) * DKH + ss * 8,          \
                    &lds[buf][(w * 64) * 8]);                                           \
        gload_lds16(vt + ((size_t)bh * DKH + row) * SEQ + (kt_) * 64 + ss * 8,          \
                    &lds[buf][4096 + (w * 64) * 8]);                                    \
    }

    STAGE(0, kt0);
    __syncthreads();

    int cur = 0;
    for (int ki = 0; ki < nkt; ++ki) {
        if (ki + 1 < nkt) STAGE(cur ^ 1, kt0 + ki + 1);

        const u16* Klds = &lds[cur][0];
        const u16* Vlds = &lds[cur][4096];

        // S^T = K . Q^T
        f32x16 st[2];
        #pragma unroll
        for (int T = 0; T < 2; ++T) {
            f32x16 acc = {};
            __builtin_amdgcn_s_setprio(1);
            #pragma unroll
            for (int c = 0; c < 4; ++c) {
                int row = T * 32 + l31;
                bf16x8 kf = *(const bf16x8*)&Klds[row * 64 + (((c * 2 + hi) ^ (row & 7)) * 8)];
                acc = __builtin_amdgcn_mfma_f32_32x32x16_bf16(kf, qf[c], acc, 0, 0, 0);
            }
            __builtin_amdgcn_s_setprio(0);
            st[T] = acc;
        }

        // online softmax (lane-local m, l; log2 domain)
        float mx[8];
        #pragma unroll
        for (int r = 0; r < 8; ++r)
            mx[r] = fmaxf(fmaxf(st[0][r], st[0][r + 8]),
                          fmaxf(st[1][r], st[1][r + 8]));
        float t0 = fmaxf(fmaxf(mx[0], mx[1]), mx[2]);
        float t1 = fmaxf(fmaxf(mx[3], mx[4]), mx[5]);
        float t2 = fmaxf(mx[6], mx[7]);
        float lmax = fmaxf(fmaxf(t0, t1), t2);
        float mloc = fmaxf(lmax, __shfl_xor(lmax, 32)) * SC;

        float mnew = fmaxf(m_r, mloc);
        if (!__all(mloc <= m_r + 11.5f)) {
            float fac = __builtin_amdgcn_exp2f(m_r - mnew);
            m_r = mnew;
            l_r *= fac;
            #pragma unroll
            for (int dt = 0; dt < 2; ++dt)
                #pragma unroll
                for (int r = 0; r < 16; ++r) ot[dt][r] *= fac;
        }

        float nm = -m_r;
        float rs0 = 0.f, rs1 = 0.f, rs2 = 0.f, rs3 = 0.f;
        #pragma unroll
        for (int T = 0; T < 2; ++T)
            #pragma unroll
            for (int r = 0; r < 16; r += 4) {
                float p0 = __builtin_amdgcn_exp2f(fmaf(st[T][r],     SC, nm));
                float p1 = __builtin_amdgcn_exp2f(fmaf(st[T][r + 1], SC, nm));
                float p2 = __builtin_amdgcn_exp2f(fmaf(st[T][r + 2], SC, nm));
                float p3 = __builtin_amdgcn_exp2f(fmaf(st[T][r + 3], SC, nm));
                st[T][r] = p0; st[T][r + 1] = p1; st[T][r + 2] = p2; st[T][r + 3] = p3;
                rs0 += p0; rs1 += p1; rs2 += p2; rs3 += p3;
            }
        float rsum = (rs0 + rs1) + (rs2 + rs3);
        l_r += rsum + __shfl_xor(rsum, 32);

        // pack P to bf16 pairs: pfrag[c] = pk[c>>1][(c&1)*4 + 0..3] (lane-local)
        u32 pk[2][8];
        #pragma unroll
        for (int T = 0; T < 2; ++T)
            #pragma unroll
            for (int g = 0; g < 8; ++g)
                pk[T][g] = cvt_pk_bf16(st[T][2 * g], st[T][2 * g + 1]);

        // O^T += V^T_perm . P^T_perm ; V chunk (c,hi) is one b128 (pre-permuted vt)
        __builtin_amdgcn_s_setprio(1);
        #pragma unroll
        for (int dt = 0; dt < 2; ++dt)
            #pragma unroll
            for (int c = 0; c < 4; ++c) {
                int row = dt * 32 + l31;
                bf16x8 vf = *(const bf16x8*)&Vlds[row * 64 + (((c * 2 + hi) ^ (row & 7)) * 8)];
                union { bf16x8 v; u32 u[4]; } pf;
                int T = c >> 1, g0 = (c & 1) * 4;
                pf.u[0] = pk[T][g0];     pf.u[1] = pk[T][g0 + 1];
                pf.u[2] = pk[T][g0 + 2]; pf.u[3] = pk[T][g0 + 3];
                ot[dt] = __builtin_amdgcn_mfma_f32_32x32x16_bf16(vf, pf.v, ot[dt], 0, 0, 0);
            }
        __builtin_amdgcn_s_setprio(0);

        __syncthreads();
        cur ^= 1;
    }

    // epilogue: (optionally normalize), bf16, wave-private LDS transpose, store
    float inv = (SPLIT == 0) ? (1.0f / l_r) : 1.0f;
    u16* dstb = (SPLIT == 0) ? aoh : (pOb + (size_t)part * PART_O_U);
    u16* tile = &lds[0][0] + w * 2048;           // 8 waves x 4KB = full 32KB (loop done)
    #pragma unroll
    for (int dt = 0; dt < 2; ++dt)
        #pragma unroll
        for (int g = 0; g < 4; ++g) {
            u32 w0 = cvt_pk_bf16(ot[dt][4 * g] * inv,     ot[dt][4 * g + 1] * inv);
            u32 w1 = cvt_pk_bf16(ot[dt][4 * g + 2] * inv, ot[dt][4 * g + 3] * inv);
            int d0 = 8 * g + 4 * hi + 32 * dt;
            int byteoff = l31 * 128 + ((d0 * 2) ^ ((l31 & 7) << 4));
            uint2 pr; pr.x = w0; pr.y = w1;
            *(uint2*)((char*)tile + byteoff) = pr;
        }
    const size_t gbase = ((size_t)bh * SEQ + qbase) * DKH;
    #pragma unroll
    for (int p = 0; p < 4; ++p) {
        int q = p * 8 + (lane >> 3);
        int byteoff = q * 128 + (((lane & 7) * 16) ^ ((q & 7) << 4));
        bf16x8 val = *(const bf16x8*)((const char*)tile + byteoff);
        *(bf16x8*)&dstb[gbase + p * 512 + lane * 8] = val;
    }
    if (SPLIT == 1 && hi == 0) {
        float2 ml; ml.x = m_r; ml.y = l_r;
        *(float2*)&pml[(size_t)part * PART_ML_F + ((size_t)bh * SEQ + qbase + l31) * 2] = ml;
    }
#undef STAGE
}

extern "C" void kernel_launch(void* const* d_in, const int* in_sizes, int n_in,
                              void* d_out, int out_size, void* d_ws, size_t ws_size,
                              hipStream_t stream)
{
    const float* q  = (const float*)d_in[0];
    const float* k  = (const float*)d_in[1];
    const float* v  = (const float*)d_in[2];
    const float* Wq = (const float*)d_in[3];
    const float* bq = (const float*)d_in[4];
    const float* Wo = (const float*)d_in[5];
    const float* bo = (const float*)d_in[6];

    char* ws = (char*)d_ws;
    u16* xb  = (u16*)(ws);               // 0..24M, dead after gemm_qkv
    u16* wqt = (u16*)(ws + OFF_WQT);
    u16* wot = (u16*)(ws + OFF_WOT);
    u16* qh  = (u16*)(ws + OFF_QH);
    u16* kh  = (u16*)(ws + OFF_KH);
    u16* vt  = (u16*)(ws + OFF_VT);      // written by gemm_qkv z=2 (xb still live)
    u16* aoh = (u16*)(ws + OFF_AOH);
    u16* pOb = (u16*)(ws + OFF_PO);
    float* pml = (float*)(ws + OFF_PML);

    prep<<<dim3(6656), dim3(256), 0, stream>>>(q, k, v, Wq, Wo, xb, wqt, wot);
    gemm_qkv<<<dim3(256, 1, 3), dim3(256), 0, stream>>>(xb, wqt, bq, qh, vt);
    if (ws_size >= (size_t)NEED_WS) {
        attn<1><<<dim3(256, 2), dim3(512), 0, stream>>>(qh, kh, vt, aoh, pOb, pml);
        gemm_o<1><<<dim3(512), dim3(256), 0, stream>>>(aoh, pOb, pml, wot, bo, (float*)d_out);
    } else {
        attn<0><<<dim3(256), dim3(512), 0, stream>>>(qh, kh, vt, aoh, pOb, pml);
        gemm_o<0><<<dim3(512), dim3(256), 0, stream>>>(aoh, pOb, pml, wot, bo, (float*)d_out);
    }
}

// Round 15
// 129.794 us; speedup vs baseline: 1.0491x; 1.0491x over previous
//
#include <hip/hip_runtime.h>
#include <hip/hip_bf16.h>

typedef unsigned short u16;
typedef unsigned int   u32;
typedef __attribute__((ext_vector_type(8))) short bf16x8;
typedef __attribute__((ext_vector_type(4))) float f32x4;
typedef __attribute__((ext_vector_type(16))) float f32x16;

#define SEQ     2048
#define DM      1024
#define NH      16
#define DKH     64
#define PER_SRC 4194304              // 4096*1024

// workspace layout (bytes) — identical to round 13
#define OFF_VT   0u
#define OFF_AOH  8388608u
#define OFF_WQT  25165824u
#define OFF_WOT  27262976u
#define OFF_QH   29360128u
#define OFF_KH   37748736u
#define OFF_VH   46137344u           // vh dead after vtrans -> hosts pml
#define OFF_PML  46137344u
#define OFF_PO   54525952u           // 2 parts * 8388608 B bf16 partial O
#define NEED_WS  71303168u
#define PART_O_U 4194304             // u16 elements per pO part
#define PART_ML_F 131072             // floats per pml part (65536 rows * 2)

__device__ __forceinline__ u16 f2bf(float f) {
    union { float f; u32 u; } c; c.f = f;
    return (u16)((c.u + 0x7fffu + ((c.u >> 16) & 1u)) >> 16);
}

__device__ __forceinline__ float bf2f(u16 h) {
    union { u32 u; float f; } c; c.u = (u32)h << 16;
    return c.f;
}

__device__ __forceinline__ u32 cvt_pk_bf16(float lo, float hi) {
    u32 r;
    asm("v_cvt_pk_bf16_f32 %0, %1, %2" : "=v"(r) : "v"(lo), "v"(hi));
    return r;
}

__device__ __forceinline__ void gload_lds16(const void* g, void* l) {
    __builtin_amdgcn_global_load_lds((__attribute__((address_space(1))) void*)g,
                                     (__attribute__((address_space(3))) void*)l,
                                     16, 0, 0);
}

// ---------------- prep: cast q/k/v fp32->bf16  +  transpose-cast W ----------
__global__ void prep(const float* __restrict__ q, const float* __restrict__ k,
                     const float* __restrict__ v, const float* __restrict__ Wq,
                     const float* __restrict__ Wo, u16* __restrict__ xb,
                     u16* __restrict__ Wqt, u16* __restrict__ Wot) {
    int bid = blockIdx.x;
    int tid = threadIdx.x;
    if (bid < 6144) {
        int srcid = bid >> 11;
        const float* src = (srcid == 0) ? q : (srcid == 1) ? k : v;
        u16* dst = xb + (size_t)srcid * PER_SRC;
        size_t i = ((size_t)(bid & 2047) * 256 + tid) * 8;
        float4 a = *(const float4*)(src + i);
        float4 b = *(const float4*)(src + i + 4);
        bf16x8 o;
        o[0] = (short)f2bf(a.x); o[1] = (short)f2bf(a.y);
        o[2] = (short)f2bf(a.z); o[3] = (short)f2bf(a.w);
        o[4] = (short)f2bf(b.x); o[5] = (short)f2bf(b.y);
        o[6] = (short)f2bf(b.z); o[7] = (short)f2bf(b.w);
        *(bf16x8*)(dst + i) = o;
    } else {
        int b2 = bid - 6144;
        const float* W = (b2 >= 256) ? Wo : Wq;
        u16* Wt       = (b2 >= 256) ? Wot : Wqt;
        int bx = b2 & 255;
        int k0 = (bx & 15) * 64;
        int n0 = (bx >> 4) * 64;
        __shared__ __align__(16) float t[64][68];
        int r = tid >> 2, cs = (tid & 3) * 16;
        #pragma unroll
        for (int j = 0; j < 4; ++j) {
            float4 vv = *(const float4*)(W + (size_t)(k0 + r) * DM + n0 + cs + j * 4);
            *(float4*)&t[r][cs + j * 4] = vv;
        }
        __syncthreads();
        bf16x8 o0, o1;
        #pragma unroll
        for (int j = 0; j < 8; ++j) o0[j] = (short)f2bf(t[cs + j][r]);
        #pragma unroll
        for (int j = 0; j < 8; ++j) o1[j] = (short)f2bf(t[cs + 8 + j][r]);
        u16* dst = Wt + (size_t)(n0 + r) * DM + k0 + cs;
        *(bf16x8*)(dst)     = o0;
        *(bf16x8*)(dst + 8) = o1;
    }
}

// ---------------- transpose vh [BH,S,64] -> vt [BH,64,S'] (chunk-permuted) ----
__global__ void vtrans(const u16* __restrict__ vh, u16* __restrict__ vt) {
    int bh = blockIdx.y, st = blockIdx.x;
    __shared__ u16 t[64][72];
    int tid = threadIdx.x;
    int r = tid >> 2, cs = (tid & 3) * 16;
    const u16* src = vh + ((size_t)bh * SEQ + st * 64 + r) * DKH + cs;
    bf16x8 v0 = *(const bf16x8*)(src);
    bf16x8 v1 = *(const bf16x8*)(src + 8);
    #pragma unroll
    for (int j = 0; j < 8; ++j) { t[r][cs + j] = (u16)v0[j]; t[r][cs + 8 + j] = (u16)v1[j]; }
    __syncthreads();
    bf16x8 o0, o1;
    #pragma unroll
    for (int j = 0; j < 8; ++j) o0[j] = (short)t[cs + j][r];
    #pragma unroll
    for (int j = 0; j < 8; ++j) o1[j] = (short)t[cs + 8 + j][r];
    bf16x8 w0, w1;   // u' = bitswap(2,3) of u
    #pragma unroll
    for (int j = 0; j < 4; ++j) {
        w0[j] = o0[j];     w0[4 + j] = o1[j];
        w1[j] = o0[4 + j]; w1[4 + j] = o1[4 + j];
    }
    u16* dst = vt + ((size_t)bh * DKH + r) * SEQ + st * 64 + cs;
    *(bf16x8*)(dst)     = w0;
    *(bf16x8*)(dst + 8) = w1;
}

// ---------------- projection GEMM: qkv = X * Wqt^T + bq ----------------------
// 128x128 tiles, XCD-affinity swizzle; out bf16 scattered to [B,H,S,64].
__global__ __launch_bounds__(256)
void gemm_qkv(const u16* __restrict__ Abase, const u16* __restrict__ Bt,
              const float* __restrict__ bias, u16* __restrict__ outbase)
{
    __shared__ __align__(16) u16 Alds[128 * 64];
    __shared__ __align__(16) u16 Blds[128 * 64];

    const int tid  = threadIdx.x;
    const int wave = tid >> 6;
    const int lane = tid & 63;
    const int low4 = lane & 15;
    const int quad = lane >> 4;
    const int bid  = blockIdx.x;
    const int xcd  = bid & 7;
    const int j    = bid >> 3;
    const int m0 = (xcd * 4 + (j >> 3)) * 128;
    const int n0 = (j & 7) * 128;
    const int wm = (wave >> 1) * 64, wn = (wave & 1) * 64;

    const u16* A = Abase + (size_t)blockIdx.z * PER_SRC;

    f32x4 acc[4][4] = {};

    for (int kt = 0; kt < DM / 64; ++kt) {
        #pragma unroll
        for (int it = 0; it < 4; ++it) {
            int seg  = it * 256 + tid;
            int row  = seg >> 3;
            int slot = seg & 7;
            int ss   = slot ^ (row & 7);
            gload_lds16(A + (size_t)(m0 + row) * DM + kt * 64 + ss * 8,
                        &Alds[(it * 256 + wave * 64) * 8]);
            gload_lds16(Bt + (size_t)(n0 + row) * DM + kt * 64 + ss * 8,
                        &Blds[(it * 256 + wave * 64) * 8]);
        }
        __syncthreads();
        #pragma unroll
        for (int kk = 0; kk < 2; ++kk) {
            bf16x8 af[4], bfr[4];
            #pragma unroll
            for (int mi = 0; mi < 4; ++mi) {
                int row = wm + mi * 16 + low4;
                af[mi] = *(const bf16x8*)&Alds[row * 64 + (((kk * 4 + quad) ^ (row & 7)) * 8)];
            }
            #pragma unroll
            for (int ni = 0; ni < 4; ++ni) {
                int row = wn + ni * 16 + low4;
                bfr[ni] = *(const bf16x8*)&Blds[row * 64 + (((kk * 4 + quad) ^ (row & 7)) * 8)];
            }
            #pragma unroll
            for (int mi = 0; mi < 4; ++mi)
                #pragma unroll
                for (int ni = 0; ni < 4; ++ni)
                    acc[mi][ni] = __builtin_amdgcn_mfma_f32_16x16x32_bf16(
                        af[mi], bfr[ni], acc[mi][ni], 0, 0, 0);
        }
        __syncthreads();
    }

    #pragma unroll
    for (int mi = 0; mi < 4; ++mi) {
        #pragma unroll
        for (int ni = 0; ni < 4; ++ni) {
            int n = n0 + wn + ni * 16 + low4;
            float bv = bias[n];
            #pragma unroll
            for (int j2 = 0; j2 < 4; ++j2) {
                int m = m0 + wm + mi * 16 + quad * 4 + j2;
                float val = acc[mi][ni][j2] + bv;
                u16* dst = outbase + (size_t)blockIdx.z * PER_SRC;
                int b = m >> 11, s = m & (SEQ - 1);
                int h = n >> 6, dd = n & 63;
                dst[(size_t)(b * NH + h) * (SEQ * DKH) + (size_t)s * DKH + dd] = f2bf(val);
            }
        }
    }
}

// ---------------- out-projection GEMM: out = AO * Wot^T + bo (fp32) ----------
// 64x128 tiles, XCD-affinity. MERGE=0: A = aoh. MERGE=1: A = two bf16 partials
// merged in-staging with per-row weights from an LDS table.
template<int MERGE>
__global__ __launch_bounds__(256)
void gemm_o(const u16* __restrict__ Abf, const u16* __restrict__ pOb,
            const float* __restrict__ pml, const u16* __restrict__ Bt,
            const float* __restrict__ bias, float* __restrict__ out)
{
    __shared__ __align__(16) u16 Alds[64 * 64];
    __shared__ __align__(16) u16 Blds[128 * 64];
    __shared__ __align__(16) float wlds[NH * 64 * 2];

    const int tid  = threadIdx.x;
    const int wave = tid >> 6;
    const int lane = tid & 63;
    const int low4 = lane & 15;
    const int quad = lane >> 4;
    const int bid  = blockIdx.x;
    const int xcd  = bid & 7;
    const int j    = bid >> 3;           // 0..63
    const int m0 = (xcd * 8 + (j >> 3)) * 64;
    const int n0 = (j & 7) * 128;
    const int wm = (wave >> 1) * 32, wn = (wave & 1) * 64;

    const int b      = m0 >> 11;
    const int s_base = m0 & (SEQ - 1);

    if (MERGE == 1) {
        #pragma unroll
        for (int idx = tid; idx < NH * 64; idx += 256) {
            int h  = idx >> 6;
            int sl = idx & 63;
            size_t row = (((size_t)(b * NH + h)) << 11) + s_base + sl;
            float2 ml1 = *(const float2*)&pml[row * 2];
            float2 ml2 = *(const float2*)&pml[PART_ML_F + row * 2];
            float m  = fmaxf(ml1.x, ml2.x);
            float w1 = __builtin_amdgcn_exp2f(ml1.x - m);
            float w2 = __builtin_amdgcn_exp2f(ml2.x - m);
            float inv = 1.0f / (ml1.y * w1 + ml2.y * w2);
            wlds[idx * 2]     = w1 * inv;
            wlds[idx * 2 + 1] = w2 * inv;
        }
        __syncthreads();
    }

    f32x4 acc[2][4] = {};

    for (int kt = 0; kt < DM / 64; ++kt) {
        #pragma unroll
        for (int it = 0; it < 2; ++it) {
            int seg  = it * 256 + tid;
            int row  = seg >> 3;             // 0..63
            int slot = seg & 7;
            int ss   = slot ^ (row & 7);
            size_t arow = (((size_t)(b * NH + kt)) << 11) + s_base + row;
            if (MERGE == 0) {
                gload_lds16(Abf + arow * DKH + ss * 8, &Alds[seg * 8]);
            } else {
                const u16* s1 = pOb + arow * DKH + ss * 8;
                const u16* s2 = s1 + PART_O_U;
                bf16x8 x = *(const bf16x8*)s1;
                bf16x8 y = *(const bf16x8*)s2;
                float a1 = wlds[(kt * 64 + row) * 2];
                float a2 = wlds[(kt * 64 + row) * 2 + 1];
                uint4 pv;
                pv.x = cvt_pk_bf16(bf2f((u16)x[0]) * a1 + bf2f((u16)y[0]) * a2,
                                   bf2f((u16)x[1]) * a1 + bf2f((u16)y[1]) * a2);
                pv.y = cvt_pk_bf16(bf2f((u16)x[2]) * a1 + bf2f((u16)y[2]) * a2,
                                   bf2f((u16)x[3]) * a1 + bf2f((u16)y[3]) * a2);
                pv.z = cvt_pk_bf16(bf2f((u16)x[4]) * a1 + bf2f((u16)y[4]) * a2,
                                   bf2f((u16)x[5]) * a1 + bf2f((u16)y[5]) * a2);
                pv.w = cvt_pk_bf16(bf2f((u16)x[6]) * a1 + bf2f((u16)y[6]) * a2,
                                   bf2f((u16)x[7]) * a1 + bf2f((u16)y[7]) * a2);
                *(uint4*)&Alds[seg * 8] = pv;
            }
        }
        #pragma unroll
        for (int it = 0; it < 4; ++it) {
            int seg  = it * 256 + tid;
            int row  = seg >> 3;             // 0..127
            int slot = seg & 7;
            int ss   = slot ^ (row & 7);
            gload_lds16(Bt + (size_t)(n0 + row) * DM + kt * 64 + ss * 8,
                        &Blds[seg * 8]);
        }
        __syncthreads();
        #pragma unroll
        for (int kk = 0; kk < 2; ++kk) {
            bf16x8 af[2], bfr[4];
            #pragma unroll
            for (int mi = 0; mi < 2; ++mi) {
                int row = wm + mi * 16 + low4;
                af[mi] = *(const bf16x8*)&Alds[row * 64 + (((kk * 4 + quad) ^ (row & 7)) * 8)];
            }
            #pragma unroll
            for (int ni = 0; ni < 4; ++ni) {
                int row = wn + ni * 16 + low4;
                bfr[ni] = *(const bf16x8*)&Blds[row * 64 + (((kk * 4 + quad) ^ (row & 7)) * 8)];
            }
            #pragma unroll
            for (int mi = 0; mi < 2; ++mi)
                #pragma unroll
                for (int ni = 0; ni < 4; ++ni)
                    acc[mi][ni] = __builtin_amdgcn_mfma_f32_16x16x32_bf16(
                        af[mi], bfr[ni], acc[mi][ni], 0, 0, 0);
        }
        __syncthreads();
    }

    #pragma unroll
    for (int mi = 0; mi < 2; ++mi) {
        #pragma unroll
        for (int ni = 0; ni < 4; ++ni) {
            int n = n0 + wn + ni * 16 + low4;
            float bv = bias[n];
            #pragma unroll
            for (int j2 = 0; j2 < 4; ++j2) {
                int m = m0 + wm + mi * 16 + quad * 4 + j2;
                out[(size_t)m * DM + n] = acc[mi][ni][j2] + bv;
            }
        }
    }
}

// ---------------- flash attention: 512 threads (8 waves share one K/V stage) -
// SPLIT=0: full pass (32 KV tiles), normalized bf16 -> aoh.
// SPLIT=1: 2-way KV split (blockIdx.y = part, 16 tiles each); UNNORMALIZED bf16
//          O~ -> pOb[part] + per-row (m,l) -> pml[part]; merged in gemm_o.
template<int SPLIT>
__global__ __launch_bounds__(512, 2)
void attn(const u16* __restrict__ qh, const u16* __restrict__ kh,
          const u16* __restrict__ vt, u16* __restrict__ aoh,
          u16* __restrict__ pOb, float* __restrict__ pml)
{
    __shared__ __align__(16) u16 lds[2][8192];   // [buf][K 4096 | V 4096]

    const int tid  = threadIdx.x;
    const int w    = tid >> 6;                   // 0..7
    const int lane = tid & 63;
    const int l31  = lane & 31;
    const int hi   = lane >> 5;

    int bid = blockIdx.x;                        // 256 blocks
    int lid = (bid & 7) * 32 + (bid >> 3);       // XCD-chunked swizzle
    const int qt = lid & 7;
    const int bh = lid >> 3;
    const int part = SPLIT ? blockIdx.y : 0;
    const int kt0  = SPLIT ? part * 16 : 0;
    const int nkt  = SPLIT ? 16 : 32;

    const int qbase = qt * 256 + w * 32;
    const int q_row = qbase + l31;

    const float SC = 0.18033688f;   // 0.125 * log2(e)

    bf16x8 qf[4];
    #pragma unroll
    for (int c = 0; c < 4; ++c)
        qf[c] = *(const bf16x8*)&qh[((size_t)bh * SEQ + q_row) * DKH + c * 16 + hi * 8];

    float m_r = -1e30f, l_r = 0.f;
    f32x16 ot[2] = {};    // O^T: col q = l31, rows d = (r&3)+8*(r>>2)+4*hi+32*dt

#define STAGE(buf, kt_)                                                                 \
    {                                                                                   \
        int row  = tid >> 3;                                                            \
        int slot = tid & 7;                                                             \
        int ss   = slot ^ (row & 7);                                                    \
        gload_lds16(kh + ((size_t)bh * SEQ + (kt_) * 64 + row) * DKH + ss * 8,          \
                    &lds[buf][(w * 64) * 8]);                                           \
        gload_lds16(vt + ((size_t)bh * DKH + row) * SEQ + (kt_) * 64 + ss * 8,          \
                    &lds[buf][4096 + (w * 64) * 8]);                                    \
    }

    STAGE(0, kt0);
    __syncthreads();

    int cur = 0;
    for (int ki = 0; ki < nkt; ++ki) {
        if (ki + 1 < nkt) STAGE(cur ^ 1, kt0 + ki + 1);

        const u16* Klds = &lds[cur][0];
        const u16* Vlds = &lds[cur][4096];

        // S^T = K . Q^T
        f32x16 st[2];
        #pragma unroll
        for (int T = 0; T < 2; ++T) {
            f32x16 acc = {};
            __builtin_amdgcn_s_setprio(1);
            #pragma unroll
            for (int c = 0; c < 4; ++c) {
                int row = T * 32 + l31;
                bf16x8 kf = *(const bf16x8*)&Klds[row * 64 + (((c * 2 + hi) ^ (row & 7)) * 8)];
                acc = __builtin_amdgcn_mfma_f32_32x32x16_bf16(kf, qf[c], acc, 0, 0, 0);
            }
            __builtin_amdgcn_s_setprio(0);
            st[T] = acc;
        }

        // online softmax (lane-local m, l; log2 domain)
        float mx[8];
        #pragma unroll
        for (int r = 0; r < 8; ++r)
            mx[r] = fmaxf(fmaxf(st[0][r], st[0][r + 8]),
                          fmaxf(st[1][r], st[1][r + 8]));
        float t0 = fmaxf(fmaxf(mx[0], mx[1]), mx[2]);
        float t1 = fmaxf(fmaxf(mx[3], mx[4]), mx[5]);
        float t2 = fmaxf(mx[6], mx[7]);
        float lmax = fmaxf(fmaxf(t0, t1), t2);
        float mloc = fmaxf(lmax, __shfl_xor(lmax, 32)) * SC;

        float mnew = fmaxf(m_r, mloc);
        if (!__all(mloc <= m_r + 11.5f)) {
            float fac = __builtin_amdgcn_exp2f(m_r - mnew);
            m_r = mnew;
            l_r *= fac;
            #pragma unroll
            for (int dt = 0; dt < 2; ++dt)
                #pragma unroll
                for (int r = 0; r < 16; ++r) ot[dt][r] *= fac;
        }

        float nm = -m_r;
        float rs0 = 0.f, rs1 = 0.f, rs2 = 0.f, rs3 = 0.f;
        #pragma unroll
        for (int T = 0; T < 2; ++T)
            #pragma unroll
            for (int r = 0; r < 16; r += 4) {
                float p0 = __builtin_amdgcn_exp2f(fmaf(st[T][r],     SC, nm));
                float p1 = __builtin_amdgcn_exp2f(fmaf(st[T][r + 1], SC, nm));
                float p2 = __builtin_amdgcn_exp2f(fmaf(st[T][r + 2], SC, nm));
                float p3 = __builtin_amdgcn_exp2f(fmaf(st[T][r + 3], SC, nm));
                st[T][r] = p0; st[T][r + 1] = p1; st[T][r + 2] = p2; st[T][r + 3] = p3;
                rs0 += p0; rs1 += p1; rs2 += p2; rs3 += p3;
            }
        float rsum = (rs0 + rs1) + (rs2 + rs3);
        l_r += rsum + __shfl_xor(rsum, 32);

        // pack P to bf16 pairs: pfrag[c] = pk[c>>1][(c&1)*4 + 0..3] (lane-local)
        u32 pk[2][8];
        #pragma unroll
        for (int T = 0; T < 2; ++T)
            #pragma unroll
            for (int g = 0; g < 8; ++g)
                pk[T][g] = cvt_pk_bf16(st[T][2 * g], st[T][2 * g + 1]);

        // O^T += V^T_perm . P^T_perm ; V chunk (c,hi) is one b128 (pre-permuted vt)
        __builtin_amdgcn_s_setprio(1);
        #pragma unroll
        for (int dt = 0; dt < 2; ++dt)
            #pragma unroll
            for (int c = 0; c < 4; ++c) {
                int row = dt * 32 + l31;
                bf16x8 vf = *(const bf16x8*)&Vlds[row * 64 + (((c * 2 + hi) ^ (row & 7)) * 8)];
                union { bf16x8 v; u32 u[4]; } pf;
                int T = c >> 1, g0 = (c & 1) * 4;
                pf.u[0] = pk[T][g0];     pf.u[1] = pk[T][g0 + 1];
                pf.u[2] = pk[T][g0 + 2]; pf.u[3] = pk[T][g0 + 3];
                ot[dt] = __builtin_amdgcn_mfma_f32_32x32x16_bf16(vf, pf.v, ot[dt], 0, 0, 0);
            }
        __builtin_amdgcn_s_setprio(0);

        __syncthreads();
        cur ^= 1;
    }

    // epilogue: (optionally normalize), bf16, wave-private LDS transpose, store
    float inv = (SPLIT == 0) ? (1.0f / l_r) : 1.0f;
    u16* dstb = (SPLIT == 0) ? aoh : (pOb + (size_t)part * PART_O_U);
    u16* tile = &lds[0][0] + w * 2048;           // 8 waves x 4KB = full 32KB (loop done)
    #pragma unroll
    for (int dt = 0; dt < 2; ++dt)
        #pragma unroll
        for (int g = 0; g < 4; ++g) {
            u32 w0 = cvt_pk_bf16(ot[dt][4 * g] * inv,     ot[dt][4 * g + 1] * inv);
            u32 w1 = cvt_pk_bf16(ot[dt][4 * g + 2] * inv, ot[dt][4 * g + 3] * inv);
            int d0 = 8 * g + 4 * hi + 32 * dt;
            int byteoff = l31 * 128 + ((d0 * 2) ^ ((l31 & 7) << 4));
            uint2 pr; pr.x = w0; pr.y = w1;
            *(uint2*)((char*)tile + byteoff) = pr;
        }
    const size_t gbase = ((size_t)bh * SEQ + qbase) * DKH;
    #pragma unroll
    for (int p = 0; p < 4; ++p) {
        int q = p * 8 + (lane >> 3);
        int byteoff = q * 128 + (((lane & 7) * 16) ^ ((q & 7) << 4));
        bf16x8 val = *(const bf16x8*)((const char*)tile + byteoff);
        *(bf16x8*)&dstb[gbase + p * 512 + lane * 8] = val;
    }
    if (SPLIT == 1 && hi == 0) {
        float2 ml; ml.x = m_r; ml.y = l_r;
        *(float2*)&pml[(size_t)part * PART_ML_F + ((size_t)bh * SEQ + qbase + l31) * 2] = ml;
    }
#undef STAGE
}

extern "C" void kernel_launch(void* const* d_in, const int* in_sizes, int n_in,
                              void* d_out, int out_size, void* d_ws, size_t ws_size,
                              hipStream_t stream)
{
    const float* q  = (const float*)d_in[0];
    const float* k  = (const float*)d_in[1];
    const float* v  = (const float*)d_in[2];
    const float* Wq = (const float*)d_in[3];
    const float* bq = (const float*)d_in[4];
    const float* Wo = (const float*)d_in[5];
    const float* bo = (const float*)d_in[6];

    char* ws = (char*)d_ws;
    u16* xb  = (u16*)(ws);               // aliases vt/aoh region (xb dead after gemm_qkv)
    u16* wqt = (u16*)(ws + OFF_WQT);
    u16* wot = (u16*)(ws + OFF_WOT);
    u16* qh  = (u16*)(ws + OFF_QH);
    u16* kh  = (u16*)(ws + OFF_KH);
    u16* vh  = (u16*)(ws + OFF_VH);
    u16* vt  = (u16*)(ws + OFF_VT);
    u16* aoh = (u16*)(ws + OFF_AOH);
    u16* pOb = (u16*)(ws + OFF_PO);
    float* pml = (float*)(ws + OFF_PML); // reuses vh region (dead after vtrans)

    prep<<<dim3(6656), dim3(256), 0, stream>>>(q, k, v, Wq, Wo, xb, wqt, wot);
    gemm_qkv<<<dim3(256, 1, 3), dim3(256), 0, stream>>>(xb, wqt, bq, qh);
    vtrans<<<dim3(32, 32), dim3(256), 0, stream>>>(vh, vt);
    if (ws_size >= (size_t)NEED_WS) {
        attn<1><<<dim3(256, 2), dim3(512), 0, stream>>>(qh, kh, vt, aoh, pOb, pml);
        gemm_o<1><<<dim3(512), dim3(256), 0, stream>>>(aoh, pOb, pml, wot, bo, (float*)d_out);
    } else {
        attn<0><<<dim3(256), dim3(512), 0, stream>>>(qh, kh, vt, aoh, pOb, pml);
        gemm_o<0><<<dim3(512), dim3(256), 0, stream>>>(aoh, pOb, pml, wot, bo, (float*)d_out);
    }
}